// Round 5
// baseline (107.269 us; speedup 1.0000x reference)
//
#include <hip/hip_runtime.h>
#include <math.h>
#include <stdint.h>

// GE2E loss on MI355X — 4-kernel pipeline, no memsets.
// out = sum_k counts[k]*log(sum_j exp(S[j,k])) - sum_i logit_self[i]
// Logits <= w*1+b = 5 -> exp without max-subtraction is safe in fp32.
// e stored normalized in bf16 (ebf); csum in bf16; dots via bf16 MFMA.
// Self logit from dot_own: u = csum_y - e; dot(e,u)=dot-1; |u|^2 = nsq - 2*dot + 1.

typedef __attribute__((ext_vector_type(8))) short bf16x8;
typedef __attribute__((ext_vector_type(4))) float f32x4;
struct alignas(16) US8 { unsigned short u[8]; };

__device__ inline float waveReduceSum(float v) {
#pragma unroll
    for (int m = 32; m >= 1; m >>= 1) v += __shfl_xor(v, m, 64);
    return v;
}
__device__ inline unsigned short f2bf(float f) {
    uint32_t u = __float_as_uint(f);
    return (unsigned short)((u + 0x7FFFu + ((u >> 16) & 1u)) >> 16);
}
__device__ inline float bf2f(unsigned short u) {
    return __uint_as_float(((uint32_t)u) << 16);
}
__device__ inline void gload_lds16(const void* g, void* l) {
    __builtin_amdgcn_global_load_lds(
        (const __attribute__((address_space(1))) uint32_t*)g,
        (__attribute__((address_space(3))) uint32_t*)l, 16, 0, 0);
}

// --- K1: normalize rows -> bf16 (one wave per row, D=512) ---
__global__ __launch_bounds__(256) void k_norms(const float* __restrict__ emb,
                                               unsigned short* __restrict__ ebf, int N) {
    int wid = threadIdx.x >> 6, l = threadIdx.x & 63;
    int row = blockIdx.x * 4 + wid;
    if (row >= N) return;
    const float4* p = reinterpret_cast<const float4*>(emb + (size_t)row * 512);
    float4 v0 = p[l * 2], v1 = p[l * 2 + 1];
    float s = v0.x * v0.x + v0.y * v0.y + v0.z * v0.z + v0.w * v0.w
            + v1.x * v1.x + v1.y * v1.y + v1.z * v1.z + v1.w * v1.w;
    s = waveReduceSum(s);
    float inv = 1.0f / fmaxf(sqrtf(s), 1e-12f);
    US8 t;
    t.u[0] = f2bf(v0.x * inv); t.u[1] = f2bf(v0.y * inv);
    t.u[2] = f2bf(v0.z * inv); t.u[3] = f2bf(v0.w * inv);
    t.u[4] = f2bf(v1.x * inv); t.u[5] = f2bf(v1.y * inv);
    t.u[6] = f2bf(v1.z * inv); t.u[7] = f2bf(v1.w * inv);
    *reinterpret_cast<US8*>(ebf + (size_t)row * 512 + l * 8) = t;
}

// --- K2: per-class centroid sums via ballot scan (block per class, 8 waves) ---
__global__ __launch_bounds__(512) void k_centroid(
        const unsigned short* __restrict__ ebf, const int* __restrict__ y,
        const float* __restrict__ wptr, unsigned short* __restrict__ csum_bf,
        float* __restrict__ normsq, float* __restrict__ colscale,
        int* __restrict__ counts, int N) {
    __shared__ float part[8][512];
    __shared__ float red[512];
    __shared__ int cnts[8];
    int c = blockIdx.x;
    int tid = threadIdx.x, l = tid & 63, w = tid >> 6;
    int chunk = N >> 3;
    float facc[8] = {0.f, 0.f, 0.f, 0.f, 0.f, 0.f, 0.f, 0.f};
    int cnt = 0;
    int iend = (w + 1) * chunk;
    for (int i0 = w * chunk; i0 < iend; i0 += 64) {
        unsigned long long m = __ballot(y[i0 + l] == c);
        cnt += (int)__popcll(m);
        while (m) {
            int b = __builtin_ctzll(m);
            m &= m - 1;
            int r = i0 + b;
            bf16x8 v = *reinterpret_cast<const bf16x8*>(ebf + (size_t)r * 512 + l * 8);
#pragma unroll
            for (int j = 0; j < 8; ++j) facc[j] += bf2f((unsigned short)v[j]);
        }
    }
#pragma unroll
    for (int j = 0; j < 4; ++j) {
        // two float4 stores
    }
    *reinterpret_cast<float4*>(&part[w][l * 8]) =
        make_float4(facc[0], facc[1], facc[2], facc[3]);
    *reinterpret_cast<float4*>(&part[w][l * 8 + 4]) =
        make_float4(facc[4], facc[5], facc[6], facc[7]);
    if (l == 0) cnts[w] = cnt;
    __syncthreads();
    float s = part[0][tid] + part[1][tid] + part[2][tid] + part[3][tid]
            + part[4][tid] + part[5][tid] + part[6][tid] + part[7][tid];
    csum_bf[(size_t)c * 512 + tid] = f2bf(s);
    red[tid] = s * s;
    __syncthreads();
    for (int o = 256; o >= 1; o >>= 1) {
        if (tid < o) red[tid] += red[tid + o];
        __syncthreads();
    }
    if (tid == 0) {
        int ct = cnts[0] + cnts[1] + cnts[2] + cnts[3]
               + cnts[4] + cnts[5] + cnts[6] + cnts[7];
        counts[c] = ct;
        float nsq = red[0];
        normsq[c] = nsq;
        colscale[c] = wptr[0] / fmaxf(sqrtf(nsq), (float)ct * 1e-8f);
    }
}

// --- K3: MFMA GEMM (ebf @ csum_bf^T), double-buffered gload_lds staging,
//         fused self-logit + exp + per-column partials + self partial ---
// BM=64, BN=128, BK=64, 2 waves. Wave w: cols w*64..+63, stages A khalf w, B khalf w.
#define NKT 8

__global__ __launch_bounds__(128) void k_gemm(
        const unsigned short* __restrict__ ebf, const unsigned short* __restrict__ csum_bf,
        const int* __restrict__ y, const float* __restrict__ colscale,
        const float* __restrict__ normsq, const int* __restrict__ counts,
        const float* __restrict__ wptr, const float* __restrict__ bptr,
        float* __restrict__ colpart, float* __restrict__ selfpart, int C) {
    __shared__ unsigned short As[2][8 * 512];    // 2 x 8 KB
    __shared__ unsigned short Bs[2][16 * 512];   // 2 x 16 KB
    __shared__ float colsum[128];
    __shared__ float selfred[2];

    const int tid = threadIdx.x;
    const int l = tid & 63;
    const int w = tid >> 6;
    const int r0 = blockIdx.x * 64;
    const int c0 = blockIdx.y * 128;
    const int rsub = l >> 2;                            // row within 16
    const int kcs = ((l & 3) ^ ((l >> 3) & 3)) * 8;     // swizzled k-chunk (ushorts)

    // A subtile st = khalf*4 + rowblk; wave w stages khalf w (sts w*4..w*4+3)
    const unsigned short* srcA[4];
#pragma unroll
    for (int i = 0; i < 4; ++i) {
        int st = w * 4 + i;
        int row = r0 + (st & 3) * 16 + rsub;
        srcA[i] = ebf + (size_t)row * 512 + (st >> 2) * 32 + kcs;
    }
    // B subtile st = khalf*8 + colblk; wave w stages khalf w (sts w*8..w*8+7)
    const unsigned short* srcB[8];
#pragma unroll
    for (int i = 0; i < 8; ++i) {
        int st = w * 8 + i;
        int col = c0 + (st & 7) * 16 + rsub;
        srcB[i] = csum_bf + (size_t)col * 512 + (st >> 3) * 32 + kcs;
    }
    // fragment read offset (ushorts): row l&15, k-chunk l>>4, same swizzle
    const int fro = (l & 15) * 32 + (((l >> 4) ^ ((l >> 1) & 3)) * 8);

    f32x4 acc[4][4];
#pragma unroll
    for (int m = 0; m < 4; ++m)
#pragma unroll
        for (int n = 0; n < 4; ++n) acc[m][n] = (f32x4){0.f, 0.f, 0.f, 0.f};

    // prologue: stage kt=0 into buf 0
#pragma unroll
    for (int i = 0; i < 4; ++i) gload_lds16(srcA[i], &As[0][(w * 4 + i) * 512]);
#pragma unroll
    for (int i = 0; i < 8; ++i) gload_lds16(srcB[i], &Bs[0][(w * 8 + i) * 512]);
    __syncthreads();

    int cur = 0;
    for (int kt = 0; kt < NKT; ++kt) {
        if (kt + 1 < NKT) {   // stage next tile into the other buffer (overlaps compute)
#pragma unroll
            for (int i = 0; i < 4; ++i)
                gload_lds16(srcA[i] + (kt + 1) * 64, &As[cur ^ 1][(w * 4 + i) * 512]);
#pragma unroll
            for (int i = 0; i < 8; ++i)
                gload_lds16(srcB[i] + (kt + 1) * 64, &Bs[cur ^ 1][(w * 8 + i) * 512]);
        }
#pragma unroll
        for (int h = 0; h < 2; ++h) {
            bf16x8 af[4];
#pragma unroll
            for (int m = 0; m < 4; ++m)
                af[m] = *reinterpret_cast<const bf16x8*>(&As[cur][(h * 4 + m) * 512 + fro]);
#pragma unroll
            for (int n = 0; n < 4; ++n) {
                bf16x8 bv = *reinterpret_cast<const bf16x8*>(
                    &Bs[cur][(h * 8 + w * 4 + n) * 512 + fro]);
#pragma unroll
                for (int m = 0; m < 4; ++m)
                    acc[m][n] = __builtin_amdgcn_mfma_f32_16x16x32_bf16(af[m], bv, acc[m][n], 0, 0, 0);
            }
        }
        __syncthreads();   // joins waves; drains next-tile loads (issued pre-compute)
        cur ^= 1;
    }

    // epilogue: C/D layout col=lane&15, row=(lane>>4)*4+j
    float bv = bptr[0], wv = wptr[0];
    int lcol = l & 15, lrow4 = (l >> 4) * 4;
    float cs[4], nsq[4], cm1[4]; int cls[4];
#pragma unroll
    for (int n = 0; n < 4; ++n) {
        int c = c0 + w * 64 + n * 16 + lcol;
        cls[n] = c; cs[n] = colscale[c]; nsq[n] = normsq[c];
        cm1[n] = (float)(counts[c] - 1);
    }
    float colacc[4] = {0.f, 0.f, 0.f, 0.f};
    float selfacc = 0.f;
#pragma unroll
    for (int m = 0; m < 4; ++m) {
#pragma unroll
        for (int j = 0; j < 4; ++j) {
            int row = r0 + m * 16 + lrow4 + j;
            int yc = y[row];
#pragma unroll
            for (int n = 0; n < 4; ++n) {
                float dot = acc[m][n][j];
                float logit;
                if (yc == cls[n]) {
                    float un2 = fmaxf(nsq[n] - 2.f * dot + 1.f, 0.f);
                    float denom = fmaxf(sqrtf(un2), cm1[n] * 1e-8f);
                    logit = wv * (dot - 1.f) / denom + bv;
                    selfacc += logit;
                } else {
                    logit = dot * cs[n] + bv;
                }
                colacc[n] += __expf(logit);
            }
        }
    }
#pragma unroll
    for (int n = 0; n < 4; ++n) {
        float v = colacc[n];
        v += __shfl_xor(v, 16, 64);
        v += __shfl_xor(v, 32, 64);
        colacc[n] = v;
    }
    selfacc = waveReduceSum(selfacc);
    if (l < 16) {
#pragma unroll
        for (int n = 0; n < 4; ++n) colsum[w * 64 + n * 16 + l] = colacc[n];
    }
    if (l == 0) selfred[w] = selfacc;
    __syncthreads();
    if (tid < 128)
        colpart[(size_t)blockIdx.x * C + c0 + tid] = colsum[tid];   // [bx][c] layout
    if (tid == 0)
        selfpart[blockIdx.y * gridDim.x + blockIdx.x] = selfred[0] + selfred[1];
}

// --- K4: finalize: per-class lse, weighted sum, minus self partials ---
__global__ __launch_bounds__(256) void k_final(
        const float* __restrict__ colpart, const int* __restrict__ counts,
        const float* __restrict__ selfpart, float* __restrict__ out, int nbx, int C) {
    __shared__ float lds[256];
    int tid = threadIdx.x;
    float s = 0.f;
    for (int i = 0; i < nbx; ++i) s += colpart[(size_t)i * C + tid];  // coalesced per i
    float v = (float)counts[tid] * logf(s);
    for (int i = tid; i < 2 * nbx; i += 256) v -= selfpart[i];
    lds[tid] = v;
    __syncthreads();
    for (int o = 128; o >= 1; o >>= 1) {
        if (tid < o) lds[tid] += lds[tid + o];
        __syncthreads();
    }
    if (tid == 0) out[0] = lds[0];
}

extern "C" void kernel_launch(void* const* d_in, const int* in_sizes, int n_in,
                              void* d_out, int out_size, void* d_ws, size_t ws_size,
                              hipStream_t stream) {
    const float* emb  = (const float*)d_in[0];
    const int*   y    = (const int*)d_in[1];
    const float* wptr = (const float*)d_in[2];
    const float* bptr = (const float*)d_in[3];
    float* out = (float*)d_out;
    int N = in_sizes[1];
    int D = in_sizes[0] / N;   // = 512
    const int C = 256;
    int nbx = N / 64;

    unsigned short* ebf     = (unsigned short*)d_ws;                 // N*D bf16
    unsigned short* csum_bf = ebf + (size_t)N * D;                   // C*D bf16
    float* colpart  = (float*)(csum_bf + (size_t)C * D);             // nbx*C
    float* selfpart = colpart + (size_t)nbx * C;                     // 2*nbx
    float* normsq   = selfpart + 2 * (size_t)nbx;                    // C
    float* colscale = normsq + C;                                    // C
    int*   counts   = (int*)(colscale + C);                          // C

    k_norms   <<<N / 4, 256, 0, stream>>>(emb, ebf, N);
    k_centroid<<<C, 512, 0, stream>>>(ebf, y, wptr, csum_bf, normsq, colscale, counts, N);
    dim3 grid(N / 64, C / 128);
    k_gemm    <<<grid, 128, 0, stream>>>(ebf, csum_bf, y, colscale, normsq, counts,
                                         wptr, bptr, colpart, selfpart, C);
    k_final   <<<1, 256, 0, stream>>>(colpart, counts, selfpart, out, nbx, C);
}

// Round 6
// 51.958 us; speedup vs baseline: 2.0645x; 2.0645x over previous
//
#include <hip/hip_runtime.h>
#include <math.h>
#include <stdint.h>

// GE2E loss on MI355X — 5-kernel pipeline, no memsets.
// out = sum_k counts[k]*log(sum_j exp(S[j,k])) - sum_i logit_self[i]
// Logits <= w*1+b = 5 -> exp without max-subtraction is safe in fp32.
// e stored normalized in bf16 (ebf); csum in bf16; dots via bf16 MFMA.
// Self logit from dot_own: u = csum_y - e; dot(e,u)=dot-1; |u|^2 = nsq - 2*dot + 1.

typedef __attribute__((ext_vector_type(8))) short bf16x8;
typedef __attribute__((ext_vector_type(4))) float f32x4;
struct alignas(16) US8 { unsigned short u[8]; };

__device__ inline float waveReduceSum(float v) {
#pragma unroll
    for (int m = 32; m >= 1; m >>= 1) v += __shfl_xor(v, m, 64);
    return v;
}
__device__ inline unsigned short f2bf(float f) {
    uint32_t u = __float_as_uint(f);
    return (unsigned short)((u + 0x7FFFu + ((u >> 16) & 1u)) >> 16);
}
__device__ inline float bf2f(unsigned short u) {
    return __uint_as_float(((uint32_t)u) << 16);
}
__device__ inline void gload_lds16(const void* g, void* l) {
    __builtin_amdgcn_global_load_lds(
        (const __attribute__((address_space(1))) uint32_t*)g,
        (__attribute__((address_space(3))) uint32_t*)l, 16, 0, 0);
}

// --- K1: normalize rows -> bf16 (one wave per row, D=512) ---
__global__ __launch_bounds__(256) void k_norms(const float* __restrict__ emb,
                                               unsigned short* __restrict__ ebf, int N) {
    int wid = threadIdx.x >> 6, l = threadIdx.x & 63;
    int row = blockIdx.x * 4 + wid;
    if (row >= N) return;
    const float4* p = reinterpret_cast<const float4*>(emb + (size_t)row * 512);
    float4 v0 = p[l * 2], v1 = p[l * 2 + 1];
    float s = v0.x * v0.x + v0.y * v0.y + v0.z * v0.z + v0.w * v0.w
            + v1.x * v1.x + v1.y * v1.y + v1.z * v1.z + v1.w * v1.w;
    s = waveReduceSum(s);
    float inv = 1.0f / fmaxf(sqrtf(s), 1e-12f);
    US8 t;
    t.u[0] = f2bf(v0.x * inv); t.u[1] = f2bf(v0.y * inv);
    t.u[2] = f2bf(v0.z * inv); t.u[3] = f2bf(v0.w * inv);
    t.u[4] = f2bf(v1.x * inv); t.u[5] = f2bf(v1.y * inv);
    t.u[6] = f2bf(v1.z * inv); t.u[7] = f2bf(v1.w * inv);
    *reinterpret_cast<US8*>(ebf + (size_t)row * 512 + l * 8) = t;
}

// --- K2: per-class centroid sums via ballot scan (block per class, 8 waves) ---
__global__ __launch_bounds__(512) void k_centroid(
        const unsigned short* __restrict__ ebf, const int* __restrict__ y,
        const float* __restrict__ wptr, unsigned short* __restrict__ csum_bf,
        float* __restrict__ normsq, float* __restrict__ colscale,
        int* __restrict__ counts, int N) {
    __shared__ float part[8][512];
    __shared__ float red[512];
    __shared__ int cnts[8];
    int c = blockIdx.x;
    int tid = threadIdx.x, l = tid & 63, w = tid >> 6;
    int chunk = N >> 3;
    float facc[8] = {0.f, 0.f, 0.f, 0.f, 0.f, 0.f, 0.f, 0.f};
    int cnt = 0;
    int iend = (w + 1) * chunk;
    for (int i0 = w * chunk; i0 < iend; i0 += 64) {
        unsigned long long m = __ballot(y[i0 + l] == c);
        cnt += (int)__popcll(m);
        while (m) {
            int b = __builtin_ctzll(m);
            m &= m - 1;
            int r = i0 + b;
            bf16x8 v = *reinterpret_cast<const bf16x8*>(ebf + (size_t)r * 512 + l * 8);
#pragma unroll
            for (int j = 0; j < 8; ++j) facc[j] += bf2f((unsigned short)v[j]);
        }
    }
    *reinterpret_cast<float4*>(&part[w][l * 8]) =
        make_float4(facc[0], facc[1], facc[2], facc[3]);
    *reinterpret_cast<float4*>(&part[w][l * 8 + 4]) =
        make_float4(facc[4], facc[5], facc[6], facc[7]);
    if (l == 0) cnts[w] = cnt;
    __syncthreads();
    float s = part[0][tid] + part[1][tid] + part[2][tid] + part[3][tid]
            + part[4][tid] + part[5][tid] + part[6][tid] + part[7][tid];
    csum_bf[(size_t)c * 512 + tid] = f2bf(s);
    red[tid] = s * s;
    __syncthreads();
    for (int o = 256; o >= 1; o >>= 1) {
        if (tid < o) red[tid] += red[tid + o];
        __syncthreads();
    }
    if (tid == 0) {
        int ct = cnts[0] + cnts[1] + cnts[2] + cnts[3]
               + cnts[4] + cnts[5] + cnts[6] + cnts[7];
        counts[c] = ct;
        float nsq = red[0];
        normsq[c] = nsq;
        colscale[c] = wptr[0] / fmaxf(sqrtf(nsq), (float)ct * 1e-8f);
    }
}

// --- K3: MFMA GEMM (ebf @ csum_bf^T), double-buffered gload_lds staging,
//         fused self-logit + exp + per-column partials + self partial ---
// BM=64, BN=128, BK=64, 2 waves. Wave w: cols w*64..+63, stages A khalf w, B khalf w.
#define NKT 8

__global__ __launch_bounds__(128) void k_gemm(
        const unsigned short* __restrict__ ebf, const unsigned short* __restrict__ csum_bf,
        const int* __restrict__ y, const float* __restrict__ colscale,
        const float* __restrict__ normsq, const int* __restrict__ counts,
        const float* __restrict__ wptr, const float* __restrict__ bptr,
        float* __restrict__ colpart, float* __restrict__ selfpart, int C) {
    __shared__ unsigned short As[2][8 * 512];    // 2 x 8 KB
    __shared__ unsigned short Bs[2][16 * 512];   // 2 x 16 KB
    __shared__ float colsum[128];
    __shared__ float selfred[2];

    const int tid = threadIdx.x;
    const int l = tid & 63;
    const int w = tid >> 6;
    const int r0 = blockIdx.x * 64;
    const int c0 = blockIdx.y * 128;
    const int rsub = l >> 2;                            // row within 16
    const int kcs = ((l & 3) ^ ((l >> 3) & 3)) * 8;     // swizzled k-chunk (ushorts)

    // A subtile st = khalf*4 + rowblk; wave w stages khalf w (sts w*4..w*4+3)
    const unsigned short* srcA[4];
#pragma unroll
    for (int i = 0; i < 4; ++i) {
        int st = w * 4 + i;
        int row = r0 + (st & 3) * 16 + rsub;
        srcA[i] = ebf + (size_t)row * 512 + (st >> 2) * 32 + kcs;
    }
    // B subtile st = khalf*8 + colblk; wave w stages khalf w (sts w*8..w*8+7)
    const unsigned short* srcB[8];
#pragma unroll
    for (int i = 0; i < 8; ++i) {
        int st = w * 8 + i;
        int col = c0 + (st & 7) * 16 + rsub;
        srcB[i] = csum_bf + (size_t)col * 512 + (st >> 3) * 32 + kcs;
    }
    // fragment read offset (ushorts): row l&15, k-chunk l>>4, same swizzle
    const int fro = (l & 15) * 32 + (((l >> 4) ^ ((l >> 1) & 3)) * 8);

    f32x4 acc[4][4];
#pragma unroll
    for (int m = 0; m < 4; ++m)
#pragma unroll
        for (int n = 0; n < 4; ++n) acc[m][n] = (f32x4){0.f, 0.f, 0.f, 0.f};

    // prologue: stage kt=0 into buf 0
#pragma unroll
    for (int i = 0; i < 4; ++i) gload_lds16(srcA[i], &As[0][(w * 4 + i) * 512]);
#pragma unroll
    for (int i = 0; i < 8; ++i) gload_lds16(srcB[i], &Bs[0][(w * 8 + i) * 512]);
    __syncthreads();

    int cur = 0;
    for (int kt = 0; kt < NKT; ++kt) {
        if (kt + 1 < NKT) {   // stage next tile into the other buffer (overlaps compute)
#pragma unroll
            for (int i = 0; i < 4; ++i)
                gload_lds16(srcA[i] + (kt + 1) * 64, &As[cur ^ 1][(w * 4 + i) * 512]);
#pragma unroll
            for (int i = 0; i < 8; ++i)
                gload_lds16(srcB[i] + (kt + 1) * 64, &Bs[cur ^ 1][(w * 8 + i) * 512]);
        }
#pragma unroll
        for (int h = 0; h < 2; ++h) {
            bf16x8 af[4];
#pragma unroll
            for (int m = 0; m < 4; ++m)
                af[m] = *reinterpret_cast<const bf16x8*>(&As[cur][(h * 4 + m) * 512 + fro]);
#pragma unroll
            for (int n = 0; n < 4; ++n) {
                bf16x8 bv = *reinterpret_cast<const bf16x8*>(
                    &Bs[cur][(h * 8 + w * 4 + n) * 512 + fro]);
#pragma unroll
                for (int m = 0; m < 4; ++m)
                    acc[m][n] = __builtin_amdgcn_mfma_f32_16x16x32_bf16(af[m], bv, acc[m][n], 0, 0, 0);
            }
        }
        __syncthreads();   // joins waves; drains next-tile loads (issued pre-compute)
        cur ^= 1;
    }

    // epilogue: C/D layout col=lane&15, row=(lane>>4)*4+j
    float bv = bptr[0], wv = wptr[0];
    int lcol = l & 15, lrow4 = (l >> 4) * 4;
    float cs[4], nsq[4], cm1[4]; int cls[4];
#pragma unroll
    for (int n = 0; n < 4; ++n) {
        int c = c0 + w * 64 + n * 16 + lcol;
        cls[n] = c; cs[n] = colscale[c]; nsq[n] = normsq[c];
        cm1[n] = (float)(counts[c] - 1);
    }
    float colacc[4] = {0.f, 0.f, 0.f, 0.f};
    float selfacc = 0.f;
#pragma unroll
    for (int m = 0; m < 4; ++m) {
#pragma unroll
        for (int j = 0; j < 4; ++j) {
            int row = r0 + m * 16 + lrow4 + j;
            int yc = y[row];
#pragma unroll
            for (int n = 0; n < 4; ++n) {
                float dot = acc[m][n][j];
                float logit;
                if (yc == cls[n]) {
                    float un2 = fmaxf(nsq[n] - 2.f * dot + 1.f, 0.f);
                    float denom = fmaxf(sqrtf(un2), cm1[n] * 1e-8f);
                    logit = wv * (dot - 1.f) / denom + bv;
                    selfacc += logit;
                } else {
                    logit = dot * cs[n] + bv;
                }
                colacc[n] += __expf(logit);
            }
        }
    }
#pragma unroll
    for (int n = 0; n < 4; ++n) {
        float v = colacc[n];
        v += __shfl_xor(v, 16, 64);
        v += __shfl_xor(v, 32, 64);
        colacc[n] = v;
    }
    selfacc = waveReduceSum(selfacc);
    if (l < 16) {
#pragma unroll
        for (int n = 0; n < 4; ++n) colsum[w * 64 + n * 16 + l] = colacc[n];
    }
    if (l == 0) selfred[w] = selfacc;
    __syncthreads();
    if (tid < 128)
        colpart[(size_t)blockIdx.x * C + c0 + tid] = colsum[tid];   // [bx][c] layout
    if (tid == 0)
        selfpart[blockIdx.y * gridDim.x + blockIdx.x] = selfred[0] + selfred[1];
}

// --- K4: per-class reduce -> contrib[c] = counts[c]*log(sum over row tiles) ---
__global__ __launch_bounds__(64) void k_colreduce(
        const float* __restrict__ colpart, const int* __restrict__ counts,
        float* __restrict__ contrib, int nbx, int C) {
    int c = blockIdx.x, l = threadIdx.x;   // 64 threads
    float s = 0.f;
    for (int i = l; i < nbx; i += 64) s += colpart[(size_t)i * C + c];
    s = waveReduceSum(s);
    if (l == 0) contrib[c] = (float)counts[c] * logf(s);
}

// --- K5: finalize: sum contribs minus self partials ---
__global__ __launch_bounds__(256) void k_final(
        const float* __restrict__ contrib, const float* __restrict__ selfpart,
        float* __restrict__ out, int nself, int C) {
    __shared__ float lds[256];
    int tid = threadIdx.x;
    float v = (tid < C) ? contrib[tid] : 0.f;
    for (int i = tid; i < nself; i += 256) v -= selfpart[i];
    lds[tid] = v;
    __syncthreads();
    for (int o = 128; o >= 1; o >>= 1) {
        if (tid < o) lds[tid] += lds[tid + o];
        __syncthreads();
    }
    if (tid == 0) out[0] = lds[0];
}

extern "C" void kernel_launch(void* const* d_in, const int* in_sizes, int n_in,
                              void* d_out, int out_size, void* d_ws, size_t ws_size,
                              hipStream_t stream) {
    const float* emb  = (const float*)d_in[0];
    const int*   y    = (const int*)d_in[1];
    const float* wptr = (const float*)d_in[2];
    const float* bptr = (const float*)d_in[3];
    float* out = (float*)d_out;
    int N = in_sizes[1];
    int D = in_sizes[0] / N;   // = 512
    const int C = 256;
    int nbx = N / 64;

    unsigned short* ebf     = (unsigned short*)d_ws;                 // N*D bf16
    unsigned short* csum_bf = ebf + (size_t)N * D;                   // C*D bf16
    float* colpart  = (float*)(csum_bf + (size_t)C * D);             // nbx*C
    float* selfpart = colpart + (size_t)nbx * C;                     // 2*nbx
    float* normsq   = selfpart + 2 * (size_t)nbx;                    // C
    float* colscale = normsq + C;                                    // C
    int*   counts   = (int*)(colscale + C);                          // C
    float* contrib  = (float*)(counts + C);                          // C

    k_norms   <<<N / 4, 256, 0, stream>>>(emb, ebf, N);
    k_centroid<<<C, 512, 0, stream>>>(ebf, y, wptr, csum_bf, normsq, colscale, counts, N);
    dim3 grid(N / 64, C / 128);
    k_gemm    <<<grid, 128, 0, stream>>>(ebf, csum_bf, y, colscale, normsq, counts,
                                         wptr, bptr, colpart, selfpart, C);
    k_colreduce<<<C, 64, 0, stream>>>(colpart, counts, contrib, nbx, C);
    k_final   <<<1, 256, 0, stream>>>(contrib, selfpart, out, 2 * nbx, C);
}

// Round 7
// 46.249 us; speedup vs baseline: 2.3194x; 1.1234x over previous
//
#include <hip/hip_runtime.h>
#include <math.h>
#include <stdint.h>

// GE2E loss on MI355X — 4-kernel pipeline, no memsets.
// out = sum_k counts[k]*log(sum_j exp(S[j,k])) - sum_i logit_self[i]
// Logits <= w*1+b = 5 -> exp without max-subtraction is safe in fp32.
// k_centroid gathers each class's rows from fp32 emb, normalizes in-wave,
// writes bf16 ebf (each row exactly once) and the class centroid sum.
// Self logit from dot_own: u = csum_y - e; dot(e,u)=dot-1; |u|^2 = nsq - 2*dot + 1.

typedef __attribute__((ext_vector_type(8))) short bf16x8;
typedef __attribute__((ext_vector_type(4))) float f32x4;
struct alignas(16) US8 { unsigned short u[8]; };

__device__ inline float waveReduceSum(float v) {
#pragma unroll
    for (int m = 32; m >= 1; m >>= 1) v += __shfl_xor(v, m, 64);
    return v;
}
__device__ inline unsigned short f2bf(float f) {
    uint32_t u = __float_as_uint(f);
    return (unsigned short)((u + 0x7FFFu + ((u >> 16) & 1u)) >> 16);
}
__device__ inline void gload_lds16(const void* g, void* l) {
    __builtin_amdgcn_global_load_lds(
        (const __attribute__((address_space(1))) uint32_t*)g,
        (__attribute__((address_space(3))) uint32_t*)l, 16, 0, 0);
}

// --- K1: fused normalize + per-class centroid (block per class, 8 waves) ---
__global__ __launch_bounds__(512) void k_centroid(
        const float* __restrict__ emb, const int* __restrict__ y,
        const float* __restrict__ wptr, unsigned short* __restrict__ ebf,
        unsigned short* __restrict__ csum_bf, float* __restrict__ normsq,
        float* __restrict__ colscale, int* __restrict__ counts, int N) {
    __shared__ float part[8][512];
    __shared__ float red[512];
    __shared__ int cnts[8];
    int c = blockIdx.x;
    int tid = threadIdx.x, l = tid & 63, w = tid >> 6;
    int chunk = N >> 3;                       // rows per wave
    float facc[8] = {0.f, 0.f, 0.f, 0.f, 0.f, 0.f, 0.f, 0.f};
    int cnt = 0;
    int iend = (w + 1) * chunk;
    for (int i0 = w * chunk; i0 < iend; i0 += 64) {
        unsigned long long m = __ballot(y[i0 + l] == c);
        cnt += (int)__popcll(m);
        while (m) {                            // m is wave-uniform
            int b = __builtin_ctzll(m);
            m &= m - 1;
            int r = i0 + b;
            const float4* pr = reinterpret_cast<const float4*>(emb + (size_t)r * 512);
            float4 v0 = pr[l * 2], v1 = pr[l * 2 + 1];
            float s = v0.x * v0.x + v0.y * v0.y + v0.z * v0.z + v0.w * v0.w
                    + v1.x * v1.x + v1.y * v1.y + v1.z * v1.z + v1.w * v1.w;
            s = waveReduceSum(s);
            float inv = 1.0f / fmaxf(sqrtf(s), 1e-12f);
            float e0 = v0.x * inv, e1 = v0.y * inv, e2 = v0.z * inv, e3 = v0.w * inv;
            float e4 = v1.x * inv, e5 = v1.y * inv, e6 = v1.z * inv, e7 = v1.w * inv;
            US8 t;
            t.u[0] = f2bf(e0); t.u[1] = f2bf(e1); t.u[2] = f2bf(e2); t.u[3] = f2bf(e3);
            t.u[4] = f2bf(e4); t.u[5] = f2bf(e5); t.u[6] = f2bf(e6); t.u[7] = f2bf(e7);
            *reinterpret_cast<US8*>(ebf + (size_t)r * 512 + l * 8) = t;
            facc[0] += e0; facc[1] += e1; facc[2] += e2; facc[3] += e3;
            facc[4] += e4; facc[5] += e5; facc[6] += e6; facc[7] += e7;
        }
    }
    *reinterpret_cast<float4*>(&part[w][l * 8]) =
        make_float4(facc[0], facc[1], facc[2], facc[3]);
    *reinterpret_cast<float4*>(&part[w][l * 8 + 4]) =
        make_float4(facc[4], facc[5], facc[6], facc[7]);
    if (l == 0) cnts[w] = cnt;
    __syncthreads();
    float s = part[0][tid] + part[1][tid] + part[2][tid] + part[3][tid]
            + part[4][tid] + part[5][tid] + part[6][tid] + part[7][tid];
    csum_bf[(size_t)c * 512 + tid] = f2bf(s);
    red[tid] = s * s;
    __syncthreads();
    for (int o = 256; o >= 1; o >>= 1) {
        if (tid < o) red[tid] += red[tid + o];
        __syncthreads();
    }
    if (tid == 0) {
        int ct = cnts[0] + cnts[1] + cnts[2] + cnts[3]
               + cnts[4] + cnts[5] + cnts[6] + cnts[7];
        counts[c] = ct;
        float nsq = red[0];
        normsq[c] = nsq;
        colscale[c] = wptr[0] / fmaxf(sqrtf(nsq), (float)ct * 1e-8f);
    }
}

// --- K2: MFMA GEMM (ebf @ csum_bf^T), double-buffered gload_lds staging,
//         fused self-logit + exp + per-column partials + self partial ---
// BM=64, BN=128, BK=64, 2 waves. Wave w: cols w*64..+63, stages A khalf w, B khalf w.
#define NKT 8

__global__ __launch_bounds__(128) void k_gemm(
        const unsigned short* __restrict__ ebf, const unsigned short* __restrict__ csum_bf,
        const int* __restrict__ y, const float* __restrict__ colscale,
        const float* __restrict__ normsq, const int* __restrict__ counts,
        const float* __restrict__ wptr, const float* __restrict__ bptr,
        float* __restrict__ colpart, float* __restrict__ selfpart, int C) {
    __shared__ unsigned short As[2][8 * 512];    // 2 x 8 KB
    __shared__ unsigned short Bs[2][16 * 512];   // 2 x 16 KB
    __shared__ float colsum[128];
    __shared__ float selfred[2];

    const int tid = threadIdx.x;
    const int l = tid & 63;
    const int w = tid >> 6;
    const int r0 = blockIdx.x * 64;
    const int c0 = blockIdx.y * 128;
    const int rsub = l >> 2;                            // row within 16
    const int kcs = ((l & 3) ^ ((l >> 3) & 3)) * 8;     // swizzled k-chunk (ushorts)

    const unsigned short* srcA[4];
#pragma unroll
    for (int i = 0; i < 4; ++i) {
        int st = w * 4 + i;
        int row = r0 + (st & 3) * 16 + rsub;
        srcA[i] = ebf + (size_t)row * 512 + (st >> 2) * 32 + kcs;
    }
    const unsigned short* srcB[8];
#pragma unroll
    for (int i = 0; i < 8; ++i) {
        int st = w * 8 + i;
        int col = c0 + (st & 7) * 16 + rsub;
        srcB[i] = csum_bf + (size_t)col * 512 + (st >> 3) * 32 + kcs;
    }
    const int fro = (l & 15) * 32 + (((l >> 4) ^ ((l >> 1) & 3)) * 8);

    f32x4 acc[4][4];
#pragma unroll
    for (int m = 0; m < 4; ++m)
#pragma unroll
        for (int n = 0; n < 4; ++n) acc[m][n] = (f32x4){0.f, 0.f, 0.f, 0.f};

#pragma unroll
    for (int i = 0; i < 4; ++i) gload_lds16(srcA[i], &As[0][(w * 4 + i) * 512]);
#pragma unroll
    for (int i = 0; i < 8; ++i) gload_lds16(srcB[i], &Bs[0][(w * 8 + i) * 512]);
    __syncthreads();

    int cur = 0;
    for (int kt = 0; kt < NKT; ++kt) {
        if (kt + 1 < NKT) {
#pragma unroll
            for (int i = 0; i < 4; ++i)
                gload_lds16(srcA[i] + (kt + 1) * 64, &As[cur ^ 1][(w * 4 + i) * 512]);
#pragma unroll
            for (int i = 0; i < 8; ++i)
                gload_lds16(srcB[i] + (kt + 1) * 64, &Bs[cur ^ 1][(w * 8 + i) * 512]);
        }
#pragma unroll
        for (int h = 0; h < 2; ++h) {
            bf16x8 af[4];
#pragma unroll
            for (int m = 0; m < 4; ++m)
                af[m] = *reinterpret_cast<const bf16x8*>(&As[cur][(h * 4 + m) * 512 + fro]);
#pragma unroll
            for (int n = 0; n < 4; ++n) {
                bf16x8 bv = *reinterpret_cast<const bf16x8*>(
                    &Bs[cur][(h * 8 + w * 4 + n) * 512 + fro]);
#pragma unroll
                for (int m = 0; m < 4; ++m)
                    acc[m][n] = __builtin_amdgcn_mfma_f32_16x16x32_bf16(af[m], bv, acc[m][n], 0, 0, 0);
            }
        }
        __syncthreads();
        cur ^= 1;
    }

    float bv = bptr[0], wv = wptr[0];
    int lcol = l & 15, lrow4 = (l >> 4) * 4;
    float cs[4], nsq[4], cm1[4]; int cls[4];
#pragma unroll
    for (int n = 0; n < 4; ++n) {
        int c = c0 + w * 64 + n * 16 + lcol;
        cls[n] = c; cs[n] = colscale[c]; nsq[n] = normsq[c];
        cm1[n] = (float)(counts[c] - 1);
    }
    float colacc[4] = {0.f, 0.f, 0.f, 0.f};
    float selfacc = 0.f;
#pragma unroll
    for (int m = 0; m < 4; ++m) {
#pragma unroll
        for (int j = 0; j < 4; ++j) {
            int row = r0 + m * 16 + lrow4 + j;
            int yc = y[row];
#pragma unroll
            for (int n = 0; n < 4; ++n) {
                float dot = acc[m][n][j];
                float logit;
                if (yc == cls[n]) {
                    float un2 = fmaxf(nsq[n] - 2.f * dot + 1.f, 0.f);
                    float denom = fmaxf(sqrtf(un2), cm1[n] * 1e-8f);
                    logit = wv * (dot - 1.f) / denom + bv;
                    selfacc += logit;
                } else {
                    logit = dot * cs[n] + bv;
                }
                colacc[n] += __expf(logit);
            }
        }
    }
#pragma unroll
    for (int n = 0; n < 4; ++n) {
        float v = colacc[n];
        v += __shfl_xor(v, 16, 64);
        v += __shfl_xor(v, 32, 64);
        colacc[n] = v;
    }
    selfacc = waveReduceSum(selfacc);
    if (l < 16) {
#pragma unroll
        for (int n = 0; n < 4; ++n) colsum[w * 64 + n * 16 + l] = colacc[n];
    }
    if (l == 0) selfred[w] = selfacc;
    __syncthreads();
    if (tid < 128)
        colpart[(size_t)blockIdx.x * C + c0 + tid] = colsum[tid];   // [bx][c] layout
    if (tid == 0)
        selfpart[blockIdx.y * gridDim.x + blockIdx.x] = selfred[0] + selfred[1];
}

// --- K3: per-class reduce -> contrib[c] = counts[c]*log(sum over row tiles) ---
__global__ __launch_bounds__(64) void k_colreduce(
        const float* __restrict__ colpart, const int* __restrict__ counts,
        float* __restrict__ contrib, int nbx, int C) {
    int c = blockIdx.x, l = threadIdx.x;
    float s = 0.f;
    for (int i = l; i < nbx; i += 64) s += colpart[(size_t)i * C + c];
    s = waveReduceSum(s);
    if (l == 0) contrib[c] = (float)counts[c] * logf(s);
}

// --- K4: finalize: sum contribs minus self partials ---
__global__ __launch_bounds__(256) void k_final(
        const float* __restrict__ contrib, const float* __restrict__ selfpart,
        float* __restrict__ out, int nself, int C) {
    __shared__ float lds[256];
    int tid = threadIdx.x;
    float v = (tid < C) ? contrib[tid] : 0.f;
    for (int i = tid; i < nself; i += 256) v -= selfpart[i];
    lds[tid] = v;
    __syncthreads();
    for (int o = 128; o >= 1; o >>= 1) {
        if (tid < o) lds[tid] += lds[tid + o];
        __syncthreads();
    }
    if (tid == 0) out[0] = lds[0];
}

extern "C" void kernel_launch(void* const* d_in, const int* in_sizes, int n_in,
                              void* d_out, int out_size, void* d_ws, size_t ws_size,
                              hipStream_t stream) {
    const float* emb  = (const float*)d_in[0];
    const int*   y    = (const int*)d_in[1];
    const float* wptr = (const float*)d_in[2];
    const float* bptr = (const float*)d_in[3];
    float* out = (float*)d_out;
    int N = in_sizes[1];
    int D = in_sizes[0] / N;   // = 512
    const int C = 256;
    int nbx = N / 64;

    unsigned short* ebf     = (unsigned short*)d_ws;                 // N*D bf16
    unsigned short* csum_bf = ebf + (size_t)N * D;                   // C*D bf16
    float* colpart  = (float*)(csum_bf + (size_t)C * D);             // nbx*C
    float* selfpart = colpart + (size_t)nbx * C;                     // 2*nbx
    float* normsq   = selfpart + 2 * (size_t)nbx;                    // C
    float* colscale = normsq + C;                                    // C
    int*   counts   = (int*)(colscale + C);                          // C
    float* contrib  = (float*)(counts + C);                          // C

    k_centroid<<<C, 512, 0, stream>>>(emb, y, wptr, ebf, csum_bf, normsq,
                                      colscale, counts, N);
    dim3 grid(N / 64, C / 128);
    k_gemm    <<<grid, 128, 0, stream>>>(ebf, csum_bf, y, colscale, normsq, counts,
                                         wptr, bptr, colpart, selfpart, C);
    k_colreduce<<<C, 64, 0, stream>>>(colpart, counts, contrib, nbx, C);
    k_final   <<<1, 256, 0, stream>>>(contrib, selfpart, out, 2 * nbx, C);
}